// Round 1
// baseline (476.931 us; speedup 1.0000x reference)
//
#include <hip/hip_runtime.h>

typedef __attribute__((ext_vector_type(4))) float f32x4;
typedef __attribute__((ext_vector_type(8))) short short8x;

#define DIM   4096
#define NB    8
#define NN    2048
#define NROWS (NB*NN)
#define NHD   8
#define NQ    7
#define NHQ   56
#define SCALE 0.04419417382415922f  /* 1/sqrt(512) */

// workspace layout (float offsets), total ~19.8 MB
#define OFF_MU     0L
#define OFF_RSTD   16384L
#define OFF_Q7     32768L    /* 7*4096 */
#define OFF_U56    61440L    /* 56*4096 */
#define OFF_A      290816L
#define OFF_D0     291072L
#define OFF_SM     291328L
#define OFF_UGBF   295424L   /* ushort region: 64*4096 ushorts */
#define OFF_SCORES 426496L   /* 16384*64 */
#define OFF_ATTN   1475072L  /* 8*8*7*2048 */
#define OFF_AM     2392576L  /* 8*8*2048 */
#define OFF_PART   2523648L  /* 8*64*4096 */
#define OFF_YRAW   4620800L  /* 64*4096 */
#define OFF_S1     4882944L
#define OFF_CTXM   4883200L  /* 8*4096 */
#define OFF_GFIN   4915968L  /* 8*4096 */

__device__ __forceinline__ unsigned short f2bf(float f) {
  union { float f; unsigned int u; } v; v.f = f;
  unsigned int r = (v.u + 0x7FFFu + ((v.u >> 16) & 1u)) >> 16;
  return (unsigned short)r;
}

__device__ __forceinline__ float blockSum256(float v, float* red) {
  #pragma unroll
  for (int m = 1; m < 64; m <<= 1) v += __shfl_xor(v, m);
  __syncthreads();
  if ((threadIdx.x & 63) == 0) red[threadIdx.x >> 6] = v;
  __syncthreads();
  return red[0] + red[1] + red[2] + red[3];
}
__device__ __forceinline__ float blockMax256(float v, float* red) {
  #pragma unroll
  for (int m = 1; m < 64; m <<= 1) v = fmaxf(v, __shfl_xor(v, m));
  __syncthreads();
  if ((threadIdx.x & 63) == 0) red[threadIdx.x >> 6] = v;
  __syncthreads();
  return fmaxf(fmaxf(red[0], red[1]), fmaxf(red[2], red[3]));
}

// ---- P0a: q[7][4096] = clip(slots) @ Wq^T + bq  (one wave per output dim d)
__global__ __launch_bounds__(256) void k_qproj(const float* __restrict__ ipw,
    const float* __restrict__ ipb, const float* __restrict__ slots, float* __restrict__ q7) {
  const int w = threadIdx.x >> 6, l = threadIdx.x & 63;
  const int d = blockIdx.x * 4 + w;
  const float* wr = ipw + (long)d * DIM;
  float acc[7] = {0,0,0,0,0,0,0};
  for (int e = l; e < DIM; e += 64) {
    float wv = wr[e];
    #pragma unroll
    for (int s = 0; s < 7; s++) {
      float sc = fminf(fmaxf(slots[(long)s*DIM + e], -10.0f), 10.0f);
      acc[s] += sc * wv;
    }
  }
  #pragma unroll
  for (int s = 0; s < 7; s++) {
    #pragma unroll
    for (int m = 1; m < 64; m <<= 1) acc[s] += __shfl_xor(acc[s], m);
  }
  if (l == 0) {
    float bq = ipb[d];
    #pragma unroll
    for (int s = 0; s < 7; s++) q7[(long)s*DIM + d] = acc[s] + bq;
  }
}

// ---- P0b: u[h*7+q][e] = scale * sum_hd q[q][h*512+hd]*Wk[h*512+hd][e]; also ugbf=bf16(u*ln_g)
__global__ __launch_bounds__(256) void k_uproj(const float* __restrict__ ipw,
    const float* __restrict__ q7, const float* __restrict__ lng,
    float* __restrict__ u56, unsigned short* __restrict__ ugbf) {
  const int h = blockIdx.y;
  const int e = blockIdx.x * 256 + threadIdx.x;
  if (h == 8) {  // zero the pad rows 56..63 of ugbf each call (ws is poisoned)
    #pragma unroll
    for (int r = 0; r < 8; r++) ugbf[(long)(56 + r)*DIM + e] = 0;
    return;
  }
  __shared__ float qs[7][512];
  for (int i = threadIdx.x; i < 7*512; i += 256) {
    int s = i / 512, hd = i % 512;
    qs[s][hd] = q7[(long)s*DIM + h*512 + hd];
  }
  __syncthreads();
  float acc[7] = {0,0,0,0,0,0,0};
  const float* wp = ipw + ((long)(DIM + h*512))*DIM + e;
  for (int hd = 0; hd < 512; hd++) {
    float wv = wp[(long)hd * DIM];
    #pragma unroll
    for (int s = 0; s < 7; s++) acc[s] += qs[s][hd] * wv;
  }
  float ge = lng[e];
  #pragma unroll
  for (int s = 0; s < 7; s++) {
    float uv = SCALE * acc[s];
    u56[(long)(h*7 + s)*DIM + e] = uv;
    ugbf[(long)(h*7 + s)*DIM + e] = f2bf(uv * ge);
  }
}

// ---- P0c: A[hq] = sum u*g ; D0[hq] = sum u*ln_b + scale*sum q*bk
__global__ __launch_bounds__(256) void k_ad(const float* __restrict__ u56,
    const float* __restrict__ q7, const float* __restrict__ lng, const float* __restrict__ lnb,
    const float* __restrict__ ipb, float* __restrict__ Aarr, float* __restrict__ D0arr) {
  __shared__ float red[4];
  const int hq = blockIdx.x, h = hq / 7, q = hq % 7;
  float pa = 0, pd = 0, pc = 0;
  for (int e = threadIdx.x; e < DIM; e += 256) {
    float uv = u56[(long)hq*DIM + e];
    pa += uv * lng[e]; pd += uv * lnb[e];
  }
  for (int hd = threadIdx.x; hd < 512; hd += 256)
    pc += q7[(long)q*DIM + h*512 + hd] * ipb[DIM + h*512 + hd];
  pa = blockSum256(pa, red);
  pd = blockSum256(pd, red);
  pc = blockSum256(pc, red);
  if (threadIdx.x == 0) { Aarr[hq] = pa; D0arr[hq] = pd + SCALE * pc; }
}

// ---- P0d: sm[e] = mean_q clip(slots)
__global__ __launch_bounds__(256) void k_smean(const float* __restrict__ slots, float* __restrict__ sm) {
  int e = blockIdx.x * 256 + threadIdx.x;
  float s = 0;
  #pragma unroll
  for (int q = 0; q < 7; q++) s += fminf(fmaxf(slots[(long)q*DIM + e], -10.0f), 10.0f);
  sm[e] = s * (1.0f / 7.0f);
}

// ---- P1: fused LN stats + scores GEMM (MFMA bf16). 16 rows/block, 1024 blocks.
__global__ __launch_bounds__(256) void k_scores(const float* __restrict__ x,
    const unsigned short* __restrict__ ugbf, const float* __restrict__ Aarr,
    const float* __restrict__ D0arr, float* __restrict__ mu_o, float* __restrict__ rstd_o,
    float* __restrict__ scores) {
  __shared__ __align__(16) unsigned short As[16 * 136];
  __shared__ __align__(16) unsigned short Bs[64 * 136];
  __shared__ float smu[16], srstd[16];
  const int tid = threadIdx.x;
  const int w = tid >> 6, l = tid & 63;
  const int rr = tid >> 5, c4 = tid & 31;
  const long row0 = (long)blockIdx.x * 16;
  const int lr = l & 15, lk = (l >> 4) * 8;
  float sx0 = 0, sx1 = 0, sxx0 = 0, sxx1 = 0;
  f32x4 acc = {0.0f, 0.0f, 0.0f, 0.0f};
  for (int kc = 0; kc < DIM; kc += 128) {
    { // stage A (fp32 -> bf16) + LN stats in fp32
      const float4 v0 = *(const float4*)(x + (row0 + rr)*DIM + kc + c4*4);
      const float4 v1 = *(const float4*)(x + (row0 + 8 + rr)*DIM + kc + c4*4);
      sx0  += v0.x + v0.y + v0.z + v0.w;
      sxx0 += v0.x*v0.x + v0.y*v0.y + v0.z*v0.z + v0.w*v0.w;
      sx1  += v1.x + v1.y + v1.z + v1.w;
      sxx1 += v1.x*v1.x + v1.y*v1.y + v1.z*v1.z + v1.w*v1.w;
      ushort4 a0; a0.x = f2bf(v0.x); a0.y = f2bf(v0.y); a0.z = f2bf(v0.z); a0.w = f2bf(v0.w);
      ushort4 a1; a1.x = f2bf(v1.x); a1.y = f2bf(v1.y); a1.z = f2bf(v1.z); a1.w = f2bf(v1.w);
      *(ushort4*)&As[rr*136 + c4*4] = a0;
      *(ushort4*)&As[(8 + rr)*136 + c4*4] = a1;
    }
    #pragma unroll
    for (int i = 0; i < 8; i++) { // stage B (already bf16)
      int r = i*8 + rr;
      ushort4 bv = *(const ushort4*)(ugbf + (long)r*DIM + kc + c4*4);
      *(ushort4*)&Bs[r*136 + c4*4] = bv;
    }
    __syncthreads();
    #pragma unroll
    for (int kk = 0; kk < 128; kk += 32) {
      short8x a = *(const short8x*)&As[lr*136 + kk + lk];
      short8x b = *(const short8x*)&Bs[(w*16 + lr)*136 + kk + lk];
      acc = __builtin_amdgcn_mfma_f32_16x16x32_bf16(a, b, acc, 0, 0, 0);
    }
    __syncthreads();
  }
  { // finalize LN stats: reduce over the 32 lanes sharing each row set
    float a0 = sx0, b0 = sxx0, a1 = sx1, b1 = sxx1;
    #pragma unroll
    for (int m = 1; m <= 16; m <<= 1) {
      a0 += __shfl_xor(a0, m); b0 += __shfl_xor(b0, m);
      a1 += __shfl_xor(a1, m); b1 += __shfl_xor(b1, m);
    }
    if ((l & 31) == 0) {
      int g = tid >> 5;
      float mu = a0 * (1.0f/DIM), var = b0 * (1.0f/DIM) - mu*mu;
      float rs = rsqrtf(var + 1e-5f);
      smu[g] = mu; srstd[g] = rs; mu_o[row0 + g] = mu; rstd_o[row0 + g] = rs;
      mu = a1 * (1.0f/DIM); var = b1 * (1.0f/DIM) - mu*mu; rs = rsqrtf(var + 1e-5f);
      smu[8 + g] = mu; srstd[8 + g] = rs; mu_o[row0 + 8 + g] = mu; rstd_o[row0 + 8 + g] = rs;
    }
  }
  __syncthreads();
  // epilogue: scores = rstd*(raw - mu*A) + D0   (C/D: col=lane&15, row=4*(lane>>4)+reg)
  int hq = w*16 + lr;
  if (hq < NHQ) {
    float Ah = Aarr[hq], Dh = D0arr[hq];
    #pragma unroll
    for (int i = 0; i < 4; i++) {
      int rl = (l >> 4)*4 + i;
      scores[(row0 + rl)*64 + hq] = srstd[rl]*(acc[i] - smu[rl]*Ah) + Dh;
    }
  }
}

// ---- P2a: softmax over n per (b,hq)
__global__ __launch_bounds__(256) void k_softmax(const float* __restrict__ scores,
    float* __restrict__ attn) {
  __shared__ float red[4];
  const int b = blockIdx.x / NHQ, hq = blockIdx.x % NHQ;
  const int tid = threadIdx.x;
  const float* sp = scores + (long)b*NN*64 + hq;
  float s[8]; float mx = -3.4e38f;
  #pragma unroll
  for (int j = 0; j < 8; j++) { s[j] = sp[(long)(tid + j*256)*64]; mx = fmaxf(mx, s[j]); }
  mx = blockMax256(mx, red);
  float sum = 0;
  #pragma unroll
  for (int j = 0; j < 8; j++) { s[j] = __expf(s[j] - mx); sum += s[j]; }
  sum = blockSum256(sum, red);
  float inv = 1.0f / sum;
  const int h = hq / NQ, q = hq % NQ;
  float* ap = attn + ((long)(b*NHD + h)*NQ + q)*NN;
  #pragma unroll
  for (int j = 0; j < 8; j++) ap[tid + j*256] = s[j] * inv;
}

// ---- P2b: am = mean_q attn ; out_attn = mean_h attn
__global__ __launch_bounds__(256) void k_means(const float* __restrict__ attn,
    float* __restrict__ am, float* __restrict__ out_attn) {
  const int b = blockIdx.x >> 3, nc = blockIdx.x & 7;
  const int n = nc*256 + threadIdx.x;
  float aq[7] = {0,0,0,0,0,0,0};
  #pragma unroll
  for (int h = 0; h < 8; h++) {
    float ah = 0;
    #pragma unroll
    for (int q = 0; q < 7; q++) {
      float v = attn[((long)(b*NHD + h)*NQ + q)*NN + n];
      aq[q] += v; ah += v;
    }
    am[((long)(b*NHD + h))*NN + n] = ah * (1.0f/7.0f);
  }
  #pragma unroll
  for (int q = 0; q < 7; q++) out_attn[((long)(b*NQ + q))*NN + n] = aq[q] * 0.125f;
}

// ---- P3: partial yraw[b,h,e] = sum_n am*rstd*x  (split over 8 n-chunks)
__global__ __launch_bounds__(256) void k_ypart(const float* __restrict__ x,
    const float* __restrict__ am, const float* __restrict__ rstd, float* __restrict__ part) {
  const int bid = blockIdx.x;
  const int b = bid >> 5, ec = (bid >> 3) & 3, nc = bid & 7;
  __shared__ float amr[8][256];
  const int tid = threadIdx.x;
  for (int i = tid; i < 2048; i += 256) {
    int h = i >> 8, nn = i & 255;
    int row = b*NN + nc*256 + nn;
    amr[h][nn] = am[((long)(b*NHD + h))*NN + nc*256 + nn] * rstd[row];
  }
  __syncthreads();
  const int e = ec*1024 + tid*4;
  float ax[8], ay[8], az[8], aw[8];
  #pragma unroll
  for (int h = 0; h < 8; h++) { ax[h]=0; ay[h]=0; az[h]=0; aw[h]=0; }
  const float* xp = x + ((long)(b*NN + nc*256))*DIM + e;
  for (int nn = 0; nn < 256; nn++) {
    const float4 xv = *(const float4*)(xp + (long)nn*DIM);
    #pragma unroll
    for (int h = 0; h < 8; h++) {
      float a = amr[h][nn];
      ax[h] += a*xv.x; ay[h] += a*xv.y; az[h] += a*xv.z; aw[h] += a*xv.w;
    }
  }
  #pragma unroll
  for (int h = 0; h < 8; h++) {
    float4 o; o.x = ax[h]; o.y = ay[h]; o.z = az[h]; o.w = aw[h];
    *(float4*)&part[((long)(nc*64 + b*8 + h))*DIM + e] = o;
  }
}

// ---- P3b: reduce the 8 partials
__global__ __launch_bounds__(256) void k_yred(const float* __restrict__ part, float* __restrict__ yraw) {
  const long i4 = (long)blockIdx.x*256 + threadIdx.x; // 65536 float4s
  const float4* p4 = (const float4*)part;
  float4 s = p4[i4];
  #pragma unroll
  for (int nc = 1; nc < 8; nc++) {
    float4 v = p4[(long)nc*65536 + i4];
    s.x += v.x; s.y += v.y; s.z += v.z; s.w += v.w;
  }
  ((float4*)yraw)[i4] = s;
}

// ---- P4a: s1[b,h] = sum_n am*mu*rstd
__global__ __launch_bounds__(256) void k_s1(const float* __restrict__ am,
    const float* __restrict__ mu, const float* __restrict__ rstd, float* __restrict__ s1) {
  __shared__ float red[4];
  const int bh = blockIdx.x, b = bh >> 3;
  float p = 0;
  for (int n = threadIdx.x; n < NN; n += 256) {
    int row = b*NN + n;
    p += am[(long)bh*NN + n] * mu[row] * rstd[row];
  }
  p = blockSum256(p, red);
  if (threadIdx.x == 0) s1[bh] = p;
}

// ---- P4b: ctxm[b][d] = Wv_row(d) . y_mean[b, d>>9, :] + bv[d]
__global__ __launch_bounds__(256) void k_ctxm(const float* __restrict__ ipw,
    const float* __restrict__ ipb, const float* __restrict__ yraw, const float* __restrict__ s1,
    const float* __restrict__ lng, const float* __restrict__ lnb, float* __restrict__ ctxm) {
  const int w = threadIdx.x >> 6, l = threadIdx.x & 63;
  const int d = blockIdx.x*4 + w;
  const int h = d >> 9;
  const float* wr = ipw + ((long)(2*DIM + d))*DIM;
  float s1v[8];
  #pragma unroll
  for (int b = 0; b < 8; b++) s1v[b] = s1[b*8 + h];
  float acc[8] = {0,0,0,0,0,0,0,0};
  for (int e = l; e < DIM; e += 64) {
    float wv = wr[e], ge = lng[e], be = lnb[e];
    #pragma unroll
    for (int b = 0; b < 8; b++) {
      float ym = ge*(yraw[((long)(b*8 + h))*DIM + e] - s1v[b]) + be;
      acc[b] += wv * ym;
    }
  }
  #pragma unroll
  for (int b = 0; b < 8; b++) {
    #pragma unroll
    for (int m = 1; m < 64; m <<= 1) acc[b] += __shfl_xor(acc[b], m);
  }
  if (l == 0) {
    float bias = ipb[2*DIM + d];
    #pragma unroll
    for (int b = 0; b < 8; b++) ctxm[(long)b*DIM + d] = acc[b] + bias;
  }
}

// ---- P4c: gfin[b][d] = tanh(alpha) * (sm[d] + out_proj_row(d).ctxm[b] + opb[d])
__global__ __launch_bounds__(256) void k_gvec(const float* __restrict__ opw,
    const float* __restrict__ opb, const float* __restrict__ ctxm, const float* __restrict__ sm,
    const float* __restrict__ alpha, float* __restrict__ gfin) {
  const int w = threadIdx.x >> 6, l = threadIdx.x & 63;
  const int d = blockIdx.x*4 + w;
  const float* wr = opw + (long)d*DIM;
  float acc[8] = {0,0,0,0,0,0,0,0};
  for (int e = l; e < DIM; e += 64) {
    float wv = wr[e];
    #pragma unroll
    for (int b = 0; b < 8; b++) acc[b] += wv * ctxm[(long)b*DIM + e];
  }
  #pragma unroll
  for (int b = 0; b < 8; b++) {
    #pragma unroll
    for (int m = 1; m < 64; m <<= 1) acc[b] += __shfl_xor(acc[b], m);
  }
  if (l == 0) {
    float t = tanhf(alpha[0]);
    float base = sm[d] + opb[d];
    #pragma unroll
    for (int b = 0; b < 8; b++) gfin[(long)b*DIM + d] = t * (base + acc[b]);
  }
}

// ---- P5: x_refined = x + g[b]
__global__ __launch_bounds__(256) void k_refine(const float* __restrict__ x,
    const float* __restrict__ gfin, float* __restrict__ out) {
  const float4* x4 = (const float4*)x;
  const float4* g4 = (const float4*)gfin;
  float4* o4 = (float4*)out;
  const long total = (long)NROWS * 1024;
  for (long i4 = (long)blockIdx.x*256 + threadIdx.x; i4 < total; i4 += (long)gridDim.x*256) {
    long b = i4 >> 21;          // 2048*4096/4 = 2^21 float4 per batch
    long e4 = i4 & 1023;
    float4 xv = x4[i4], gv = g4[b*1024 + e4];
    float4 o; o.x = xv.x + gv.x; o.y = xv.y + gv.y; o.z = xv.z + gv.z; o.w = xv.w + gv.w;
    o4[i4] = o;
  }
}

extern "C" void kernel_launch(void* const* d_in, const int* in_sizes, int n_in,
                              void* d_out, int out_size, void* d_ws, size_t ws_size,
                              hipStream_t stream) {
  const float* x     = (const float*)d_in[0];
  const float* slots = (const float*)d_in[1];
  const float* lng   = (const float*)d_in[2];
  const float* lnb   = (const float*)d_in[3];
  const float* ipw   = (const float*)d_in[4];
  const float* ipb   = (const float*)d_in[5];
  const float* opw   = (const float*)d_in[6];
  const float* opb   = (const float*)d_in[7];
  const float* alpha = (const float*)d_in[8];
  float* out = (float*)d_out;
  float* ws  = (float*)d_ws;

  float* mu     = ws + OFF_MU;
  float* rstd   = ws + OFF_RSTD;
  float* q7     = ws + OFF_Q7;
  float* u56    = ws + OFF_U56;
  float* Aarr   = ws + OFF_A;
  float* D0arr  = ws + OFF_D0;
  float* sm     = ws + OFF_SM;
  unsigned short* ugbf = (unsigned short*)(ws + OFF_UGBF);
  float* scores = ws + OFF_SCORES;
  float* attn   = ws + OFF_ATTN;
  float* am     = ws + OFF_AM;
  float* part   = ws + OFF_PART;
  float* yraw   = ws + OFF_YRAW;
  float* s1     = ws + OFF_S1;
  float* ctxm   = ws + OFF_CTXM;
  float* gfin   = ws + OFF_GFIN;
  float* out_attn = out + (long)NROWS * DIM;

  hipLaunchKernelGGL(k_qproj,   dim3(1024),   dim3(256), 0, stream, ipw, ipb, slots, q7);
  hipLaunchKernelGGL(k_uproj,   dim3(16, 9),  dim3(256), 0, stream, ipw, q7, lng, u56, ugbf);
  hipLaunchKernelGGL(k_ad,      dim3(56),     dim3(256), 0, stream, u56, q7, lng, lnb, ipb, Aarr, D0arr);
  hipLaunchKernelGGL(k_smean,   dim3(16),     dim3(256), 0, stream, slots, sm);
  hipLaunchKernelGGL(k_scores,  dim3(1024),   dim3(256), 0, stream, x, ugbf, Aarr, D0arr, mu, rstd, scores);
  hipLaunchKernelGGL(k_softmax, dim3(448),    dim3(256), 0, stream, scores, attn);
  hipLaunchKernelGGL(k_means,   dim3(64),     dim3(256), 0, stream, attn, am, out_attn);
  hipLaunchKernelGGL(k_ypart,   dim3(256),    dim3(256), 0, stream, x, am, rstd, part);
  hipLaunchKernelGGL(k_yred,    dim3(256),    dim3(256), 0, stream, part, yraw);
  hipLaunchKernelGGL(k_s1,      dim3(64),     dim3(256), 0, stream, am, mu, rstd, s1);
  hipLaunchKernelGGL(k_ctxm,    dim3(1024),   dim3(256), 0, stream, ipw, ipb, yraw, s1, lng, lnb, ctxm);
  hipLaunchKernelGGL(k_gvec,    dim3(1024),   dim3(256), 0, stream, opw, opb, ctxm, sm, alpha, gfin);
  hipLaunchKernelGGL(k_refine,  dim3(8192),   dim3(256), 0, stream, x, gfin, out);
}

// Round 3
// 406.434 us; speedup vs baseline: 1.1735x; 1.1735x over previous
//
#include <hip/hip_runtime.h>

typedef __attribute__((ext_vector_type(4))) float f32x4;
typedef __attribute__((ext_vector_type(8))) short short8x;

#define DIM   4096
#define NB    8
#define NN    2048
#define NROWS (NB*NN)
#define NHD   8
#define NQ    7
#define NHQ   56
#define SCALE 0.04419417382415922f  /* 1/sqrt(512) */

// ---- workspace layout (float offsets), ~28.8 MB total
#define OFF_MU     0L
#define OFF_RSTD   16384L
#define OFF_Q7     32768L     /* 7*4096 */
#define OFF_SC7    61440L     /* 7*4096 clipped slots */
#define OFF_U56    90112L     /* 56*4096 */
#define OFF_A      319488L
#define OFF_D0     319552L
#define OFF_SM     319616L
#define OFF_S1     323712L
#define OFF_CTXM   323776L    /* 8*4096 */
#define OFF_GFIN   356544L    /* 8*4096 */
#define OFF_YM     389312L    /* 64*4096 */
#define OFF_UGBF   651456L    /* 64*4096 ushorts = 131072 floats (ends 782528) */
#define OFF_STATP  782528L    /* 4*16384 float2 = 131072 floats (ends 913600) */
#define OFF_SCT    913600L    /* 64*16384 transposed scores (ends 1962176) */
#define OFF_BIG    1962176L   /* 5242880 floats, time-shared: */
        /* phase A: upart 4*56*4096=917504 (uproj->ured)            */
        /* phase B: raw 4*16384*64=4194304 (scores2->sepi)          */
        /* phase C: attn@+0 (917504) am@+917504 part@+1048576 (16MB)*/
#define OFF_ATTN   (OFF_BIG)
#define OFF_AM     (OFF_BIG + 917504L)
#define OFF_PART   (OFF_BIG + 1048576L)

__device__ __forceinline__ unsigned short f2bf(float f) {   // RNE
  union { float f; unsigned int u; } v; v.f = f;
  return (unsigned short)((v.u + 0x7FFFu + ((v.u >> 16) & 1u)) >> 16);
}
__device__ __forceinline__ unsigned short f2bfr(float f) {  // cheap round
  union { float f; unsigned int u; } v; v.f = f;
  return (unsigned short)((v.u + 0x8000u) >> 16);
}

__device__ __forceinline__ float blockSum256(float v, float* red) {
  #pragma unroll
  for (int m = 1; m < 64; m <<= 1) v += __shfl_xor(v, m);
  __syncthreads();
  if ((threadIdx.x & 63) == 0) red[threadIdx.x >> 6] = v;
  __syncthreads();
  return red[0] + red[1] + red[2] + red[3];
}
__device__ __forceinline__ float blockMax256(float v, float* red) {
  #pragma unroll
  for (int m = 1; m < 64; m <<= 1) v = fmaxf(v, __shfl_xor(v, m));
  __syncthreads();
  if ((threadIdx.x & 63) == 0) red[threadIdx.x >> 6] = v;
  __syncthreads();
  return fmaxf(fmaxf(red[0], red[1]), fmaxf(red[2], red[3]));
}

// ---- P0a: sc7 = clip(slots); sm = mean_q sc7
__global__ __launch_bounds__(256) void k_smean(const float* __restrict__ slots,
    float* __restrict__ sm, float* __restrict__ sc7) {
  int e = blockIdx.x * 256 + threadIdx.x;
  float s = 0;
  #pragma unroll
  for (int q = 0; q < 7; q++) {
    float v = fminf(fmaxf(slots[(long)q*DIM + e], -10.0f), 10.0f);
    sc7[(long)q*DIM + e] = v;
    s += v;
  }
  sm[e] = s * (1.0f / 7.0f);
}

// ---- P0b: q7 = sc7 @ Wq^T + bq  (one wave per d, float4)
__global__ __launch_bounds__(256) void k_qproj(const float* __restrict__ ipw,
    const float* __restrict__ ipb, const float* __restrict__ sc7, float* __restrict__ q7) {
  const int w = threadIdx.x >> 6, l = threadIdx.x & 63;
  const int d = blockIdx.x * 4 + w;
  const float4* wr4 = (const float4*)(ipw + (long)d * DIM);
  float acc[7] = {0,0,0,0,0,0,0};
  for (int e4 = l; e4 < 1024; e4 += 64) {
    float4 wv = wr4[e4];
    #pragma unroll
    for (int s = 0; s < 7; s++) {
      float4 sv = ((const float4*)(sc7 + (long)s*DIM))[e4];
      acc[s] += wv.x*sv.x + wv.y*sv.y + wv.z*sv.z + wv.w*sv.w;
    }
  }
  #pragma unroll
  for (int s = 0; s < 7; s++) {
    #pragma unroll
    for (int m = 1; m < 64; m <<= 1) acc[s] += __shfl_xor(acc[s], m);
  }
  if (l == 0) {
    float bq = ipb[d];
    #pragma unroll
    for (int s = 0; s < 7; s++) q7[(long)s*DIM + d] = acc[s] + bq;
  }
}

// ---- P0c: partial u: upart[(c*8+h)*7+s][e] = sum_{hd in chunk c} q7*Wk
__global__ __launch_bounds__(256) void k_uproj(const float* __restrict__ ipw,
    const float* __restrict__ q7, float* __restrict__ upart) {
  const int h = blockIdx.y, c = blockIdx.z;
  const int e = blockIdx.x * 256 + threadIdx.x;
  __shared__ float qs[7][128];
  for (int i = threadIdx.x; i < 7*128; i += 256) {
    int s = i >> 7, hd = i & 127;
    qs[s][hd] = q7[(long)s*DIM + h*512 + c*128 + hd];
  }
  __syncthreads();
  float acc[7] = {0,0,0,0,0,0,0};
  const float* wp = ipw + ((long)(DIM + h*512 + c*128))*DIM + e;
  for (int hd = 0; hd < 128; hd++) {
    float wv = wp[(long)hd * DIM];
    #pragma unroll
    for (int s = 0; s < 7; s++) acc[s] += qs[s][hd] * wv;
  }
  #pragma unroll
  for (int s = 0; s < 7; s++) upart[(long)((c*8 + h)*7 + s)*DIM + e] = acc[s];
}

// ---- P0d: u56 = scale*sum_c upart; ugbf = bf16(u*ln_g); pad rows 56..63 = 0
__global__ __launch_bounds__(256) void k_ured(const float* __restrict__ upart,
    const float* __restrict__ lng, float* __restrict__ u56, unsigned short* __restrict__ ugbf) {
  const int h = blockIdx.y;
  const int e = blockIdx.x * 256 + threadIdx.x;
  if (h == 8) {
    #pragma unroll
    for (int r = 0; r < 8; r++) ugbf[(long)(56 + r)*DIM + e] = 0;
    return;
  }
  float ge = lng[e];
  #pragma unroll
  for (int s = 0; s < 7; s++) {
    float u = 0;
    #pragma unroll
    for (int c = 0; c < 4; c++) u += upart[(long)((c*8 + h)*7 + s)*DIM + e];
    u *= SCALE;
    u56[(long)(h*7 + s)*DIM + e] = u;
    ugbf[(long)(h*7 + s)*DIM + e] = f2bf(u * ge);
  }
}

// ---- P0e: A[hq] = sum u*ln_g ; D0[hq] = sum u*ln_b + scale*sum q*bk
__global__ __launch_bounds__(256) void k_ad(const float* __restrict__ u56,
    const float* __restrict__ q7, const float* __restrict__ lng, const float* __restrict__ lnb,
    const float* __restrict__ ipb, float* __restrict__ Aarr, float* __restrict__ D0arr) {
  __shared__ float red[4];
  const int hq = blockIdx.x, h = hq / 7, q = hq % 7;
  float pa = 0, pd = 0, pc = 0;
  for (int e = threadIdx.x; e < DIM; e += 256) {
    float uv = u56[(long)hq*DIM + e];
    pa += uv * lng[e]; pd += uv * lnb[e];
  }
  for (int hd = threadIdx.x; hd < 512; hd += 256)
    pc += q7[(long)q*DIM + h*512 + hd] * ipb[DIM + h*512 + hd];
  pa = blockSum256(pa, red);
  pd = blockSum256(pd, red);
  pc = blockSum256(pc, red);
  if (threadIdx.x == 0) { Aarr[hq] = pa; D0arr[hq] = pd + SCALE * pc; }
}

// ---- P1: barrier-free raw scores + LN-stat partials. K split 4-way.
// grid: blockIdx.x = rowblk*4 + ks; 4 waves/block, 16 rows/wave.
__global__ __launch_bounds__(256) void k_scores2(const float* __restrict__ x,
    const unsigned short* __restrict__ ugbf, float* __restrict__ raw, float2* __restrict__ statp) {
  const int tid = threadIdx.x;
  const int w = tid >> 6, l = tid & 63;
  const int lr = l & 15, lk8 = (l >> 4) * 8;
  const int rowblk = blockIdx.x >> 2, ks = blockIdx.x & 3;
  const int row0w = rowblk * 64 + w * 16;
  const long arow = (long)(row0w + lr) * DIM;
  const int kbase = ks * 1024;
  f32x4 acc0 = {0,0,0,0}, acc1 = {0,0,0,0}, acc2 = {0,0,0,0}, acc3 = {0,0,0,0};
  float sx = 0.f, sxx = 0.f;
  const long b0 = (long)(0*16 + lr)*DIM, b1 = (long)(1*16 + lr)*DIM,
             b2 = (long)(2*16 + lr)*DIM, b3 = (long)(3*16 + lr)*DIM;
  #pragma unroll 2
  for (int kc = kbase; kc < kbase + 1024; kc += 32) {
    const float4 v0 = *(const float4*)(x + arow + kc + lk8);
    const float4 v1 = *(const float4*)(x + arow + kc + lk8 + 4);
    sx  += (v0.x + v0.y) + (v0.z + v0.w) + (v1.x + v1.y) + (v1.z + v1.w);
    sxx += v0.x*v0.x + v0.y*v0.y + v0.z*v0.z + v0.w*v0.w
         + v1.x*v1.x + v1.y*v1.y + v1.z*v1.z + v1.w*v1.w;
    short8x a;
    a[0] = (short)f2bfr(v0.x); a[1] = (short)f2bfr(v0.y);
    a[2] = (short)f2bfr(v0.z); a[3] = (short)f2bfr(v0.w);
    a[4] = (short)f2bfr(v1.x); a[5] = (short)f2bfr(v1.y);
    a[6] = (short)f2bfr(v1.z); a[7] = (short)f2bfr(v1.w);
    short8x bb0 = *(const short8x*)(ugbf + b0 + kc + lk8);
    acc0 = __builtin_amdgcn_mfma_f32_16x16x32_bf16(a, bb0, acc0, 0, 0, 0);
    short8x bb1 = *(const short8x*)(ugbf + b1 + kc + lk8);
    acc1 = __builtin_amdgcn_mfma_f32_16x16x32_bf16(a, bb1, acc1, 0, 0, 0);
    short8x bb2 = *(const short8x*)(ugbf + b2 + kc + lk8);
    acc2 = __builtin_amdgcn_mfma_f32_16x16x32_bf16(a, bb2, acc2, 0, 0, 0);
    short8x bb3 = *(const short8x*)(ugbf + b3 + kc + lk8);
    acc3 = __builtin_amdgcn_mfma_f32_16x16x32_bf16(a, bb3, acc3, 0, 0, 0);
  }
  sx += __shfl_xor(sx, 16);  sx += __shfl_xor(sx, 32);
  sxx += __shfl_xor(sxx, 16); sxx += __shfl_xor(sxx, 32);
  if (l < 16) {
    float2 p; p.x = sx; p.y = sxx;
    statp[(long)ks*NROWS + row0w + l] = p;
  }
  const long base = ((long)ks*NROWS + row0w) * 64;
  #pragma unroll
  for (int i = 0; i < 4; i++) {
    long ro = base + (long)((l >> 4)*4 + i) * 64 + lr;
    raw[ro +  0] = acc0[i];
    raw[ro + 16] = acc1[i];
    raw[ro + 32] = acc2[i];
    raw[ro + 48] = acc3[i];
  }
}

// ---- P1b: combine K-split partials, finalize LN, write transposed scores
__global__ __launch_bounds__(256) void k_sepi(const float* __restrict__ raw,
    const float2* __restrict__ statp, const float* __restrict__ Aarr,
    const float* __restrict__ D0arr, float* __restrict__ mu_o, float* __restrict__ rstd_o,
    float* __restrict__ sct) {
  const int w = threadIdx.x >> 6, l = threadIdx.x & 63;
  const int row = blockIdx.x * 4 + w;
  float s = 0;
  #pragma unroll
  for (int ks = 0; ks < 4; ks++) s += raw[((long)ks*NROWS + row)*64 + l];
  float sx = 0, sxx = 0;
  #pragma unroll
  for (int ks = 0; ks < 4; ks++) {
    float2 p = statp[(long)ks*NROWS + row];
    sx += p.x; sxx += p.y;
  }
  float mu = sx * (1.0f/DIM), var = sxx * (1.0f/DIM) - mu*mu;
  float rs = rsqrtf(var + 1e-5f);
  if (l == 0) { mu_o[row] = mu; rstd_o[row] = rs; }
  if (l < NHQ) sct[(long)l*NROWS + row] = rs*(s - mu*Aarr[l]) + D0arr[l];
}

// ---- P2a: softmax over n per (b,hq), coalesced reads of transposed scores
__global__ __launch_bounds__(256) void k_softmax(const float* __restrict__ sct,
    float* __restrict__ attn) {
  __shared__ float red[4];
  const int b = blockIdx.x / NHQ, hq = blockIdx.x % NHQ;
  const int tid = threadIdx.x;
  const float* sp = sct + (long)hq*NROWS + (long)b*NN;
  float s[8]; float mx = -3.4e38f;
  #pragma unroll
  for (int j = 0; j < 8; j++) { s[j] = sp[tid + j*256]; mx = fmaxf(mx, s[j]); }
  mx = blockMax256(mx, red);
  float sum = 0;
  #pragma unroll
  for (int j = 0; j < 8; j++) { s[j] = __expf(s[j] - mx); sum += s[j]; }
  sum = blockSum256(sum, red);
  float inv = 1.0f / sum;
  const int h = hq / NQ, q = hq % NQ;
  float* ap = attn + ((long)(b*NHD + h)*NQ + q)*NN;
  #pragma unroll
  for (int j = 0; j < 8; j++) ap[tid + j*256] = s[j] * inv;
}

// ---- P2b: am = mean_q attn ; out_attn = mean_h attn
__global__ __launch_bounds__(256) void k_means(const float* __restrict__ attn,
    float* __restrict__ am, float* __restrict__ out_attn) {
  const int b = blockIdx.x >> 3, nc = blockIdx.x & 7;
  const int n = nc*256 + threadIdx.x;
  float aq[7] = {0,0,0,0,0,0,0};
  #pragma unroll
  for (int h = 0; h < 8; h++) {
    float ah = 0;
    #pragma unroll
    for (int q = 0; q < 7; q++) {
      float v = attn[((long)(b*NHD + h)*NQ + q)*NN + n];
      aq[q] += v; ah += v;
    }
    am[((long)(b*NHD + h))*NN + n] = ah * (1.0f/7.0f);
  }
  #pragma unroll
  for (int q = 0; q < 7; q++) out_attn[((long)(b*NQ + q))*NN + n] = aq[q] * 0.125f;
}

// ---- P2c: s1[b,h] = sum_n am*mu*rstd
__global__ __launch_bounds__(256) void k_s1(const float* __restrict__ am,
    const float* __restrict__ mu, const float* __restrict__ rstd, float* __restrict__ s1) {
  __shared__ float red[4];
  const int bh = blockIdx.x, b = bh >> 3;
  float p = 0;
  for (int n = threadIdx.x; n < NN; n += 256) {
    int row = b*NN + n;
    p += am[(long)bh*NN + n] * mu[row] * rstd[row];
  }
  p = blockSum256(p, red);
  if (threadIdx.x == 0) s1[bh] = p;
}

// ---- P3: partial yraw over 16 n-chunks of 128 rows. grid 512 (b*64+ec*16+nc)
__global__ __launch_bounds__(256) void k_ypart(const float* __restrict__ x,
    const float* __restrict__ am, const float* __restrict__ rstd, float* __restrict__ part) {
  const int bid = blockIdx.x;
  const int b = bid >> 6, ec = (bid >> 4) & 3, nc = bid & 15;
  __shared__ float amr[8][128];
  const int tid = threadIdx.x;
  for (int i = tid; i < 1024; i += 256) {
    int h = i >> 7, nn = i & 127;
    int row = b*NN + nc*128 + nn;
    amr[h][nn] = am[((long)(b*NHD + h))*NN + nc*128 + nn] * rstd[row];
  }
  __syncthreads();
  const int e = ec*1024 + tid*4;
  float ax[8], ay[8], az[8], aw[8];
  #pragma unroll
  for (int h = 0; h < 8; h++) { ax[h]=0; ay[h]=0; az[h]=0; aw[h]=0; }
  const float* xp = x + ((long)(b*NN + nc*128))*DIM + e;
  #pragma unroll 2
  for (int nn = 0; nn < 128; nn++) {
    const float4 xv = *(const float4*)(xp + (long)nn*DIM);
    #pragma unroll
    for (int h = 0; h < 8; h++) {
      float a = amr[h][nn];
      ax[h] += a*xv.x; ay[h] += a*xv.y; az[h] += a*xv.z; aw[h] += a*xv.w;
    }
  }
  #pragma unroll
  for (int h = 0; h < 8; h++) {
    float4 o; o.x = ax[h]; o.y = ay[h]; o.z = az[h]; o.w = aw[h];
    *(float4*)&part[((long)(nc*64 + b*8 + h))*DIM + e] = o;
  }
}

// ---- P3b: reduce 16 partials; fuse ym = ln_g*(y - s1) + ln_b
__global__ __launch_bounds__(256) void k_yred(const float* __restrict__ part,
    const float* __restrict__ s1, const float* __restrict__ lng, const float* __restrict__ lnb,
    float* __restrict__ ym) {
  const long i4 = (long)blockIdx.x*256 + threadIdx.x; // 65536 float4s
  const float4* p4 = (const float4*)part;
  float4 s = p4[i4];
  #pragma unroll
  for (int nc = 1; nc < 16; nc++) {
    float4 v = p4[(long)nc*65536 + i4];
    s.x += v.x; s.y += v.y; s.z += v.z; s.w += v.w;
  }
  const int bh = (int)(i4 >> 10), e4 = (int)(i4 & 1023);
  float sv = s1[bh];
  float4 g = ((const float4*)lng)[e4], bb = ((const float4*)lnb)[e4];
  float4 o;
  o.x = g.x*(s.x - sv) + bb.x; o.y = g.y*(s.y - sv) + bb.y;
  o.z = g.z*(s.z - sv) + bb.z; o.w = g.w*(s.w - sv) + bb.w;
  ((float4*)ym)[i4] = o;
}

// ---- P4a: ctxm[b][d] = Wv_row(d) . ym[b, d>>9, :] + bv[d]  (float4)
__global__ __launch_bounds__(256) void k_ctxm(const float* __restrict__ ipw,
    const float* __restrict__ ipb, const float* __restrict__ ym, float* __restrict__ ctxm) {
  const int w = threadIdx.x >> 6, l = threadIdx.x & 63;
  const int d = blockIdx.x*4 + w;
  const int h = d >> 9;
  const float4* wr4 = (const float4*)(ipw + ((long)(2*DIM + d))*DIM);
  float acc[8] = {0,0,0,0,0,0,0,0};
  for (int e4 = l; e4 < 1024; e4 += 64) {
    float4 wv = wr4[e4];
    #pragma unroll
    for (int b = 0; b < 8; b++) {
      float4 y = ((const float4*)(ym + (long)(b*8 + h)*DIM))[e4];
      acc[b] += wv.x*y.x + wv.y*y.y + wv.z*y.z + wv.w*y.w;
    }
  }
  #pragma unroll
  for (int b = 0; b < 8; b++) {
    #pragma unroll
    for (int m = 1; m < 64; m <<= 1) acc[b] += __shfl_xor(acc[b], m);
  }
  if (l == 0) {
    float bias = ipb[2*DIM + d];
    #pragma unroll
    for (int b = 0; b < 8; b++) ctxm[(long)b*DIM + d] = acc[b] + bias;
  }
}

// ---- P4b: gfin[b][d] = tanh(alpha) * (sm[d] + opw_row(d).ctxm[b] + opb[d])
__global__ __launch_bounds__(256) void k_gvec(const float* __restrict__ opw,
    const float* __restrict__ opb, const float* __restrict__ ctxm, const float* __restrict__ sm,
    const float* __restrict__ alpha, float* __restrict__ gfin) {
  const int w = threadIdx.x >> 6, l = threadIdx.x & 63;
  const int d = blockIdx.x*4 + w;
  const float4* wr4 = (const float4*)(opw + (long)d*DIM);
  float acc[8] = {0,0,0,0,0,0,0,0};
  for (int e4 = l; e4 < 1024; e4 += 64) {
    float4 wv = wr4[e4];
    #pragma unroll
    for (int b = 0; b < 8; b++) {
      float4 c = ((const float4*)(ctxm + (long)b*DIM))[e4];
      acc[b] += wv.x*c.x + wv.y*c.y + wv.z*c.z + wv.w*c.w;
    }
  }
  #pragma unroll
  for (int b = 0; b < 8; b++) {
    #pragma unroll
    for (int m = 1; m < 64; m <<= 1) acc[b] += __shfl_xor(acc[b], m);
  }
  if (l == 0) {
    float t = tanhf(alpha[0]);
    float base = sm[d] + opb[d];
    #pragma unroll
    for (int b = 0; b < 8; b++) gfin[(long)b*DIM + d] = t * (base + acc[b]);
  }
}

// ---- P5: x_refined = x + g[b]
__global__ __launch_bounds__(256) void k_refine(const float* __restrict__ x,
    const float* __restrict__ gfin, float* __restrict__ out) {
  const float4* x4 = (const float4*)x;
  const float4* g4 = (const float4*)gfin;
  float4* o4 = (float4*)out;
  const long total = (long)NROWS * 1024;
  for (long i4 = (long)blockIdx.x*256 + threadIdx.x; i4 < total; i4 += (long)gridDim.x*256) {
    long b = i4 >> 21;
    long e4 = i4 & 1023;
    float4 xv = x4[i4], gv = g4[b*1024 + e4];
    float4 o; o.x = xv.x + gv.x; o.y = xv.y + gv.y; o.z = xv.z + gv.z; o.w = xv.w + gv.w;
    o4[i4] = o;
  }
}

extern "C" void kernel_launch(void* const* d_in, const int* in_sizes, int n_in,
                              void* d_out, int out_size, void* d_ws, size_t ws_size,
                              hipStream_t stream) {
  const float* x     = (const float*)d_in[0];
  const float* slots = (const float*)d_in[1];
  const float* lng   = (const float*)d_in[2];
  const float* lnb   = (const float*)d_in[3];
  const float* ipw   = (const float*)d_in[4];
  const float* ipb   = (const float*)d_in[5];
  const float* opw   = (const float*)d_in[6];
  const float* opb   = (const float*)d_in[7];
  const float* alpha = (const float*)d_in[8];
  float* out = (float*)d_out;
  float* ws  = (float*)d_ws;

  float* mu     = ws + OFF_MU;
  float* rstd   = ws + OFF_RSTD;
  float* q7     = ws + OFF_Q7;
  float* sc7    = ws + OFF_SC7;
  float* u56    = ws + OFF_U56;
  float* Aarr   = ws + OFF_A;
  float* D0arr  = ws + OFF_D0;
  float* sm     = ws + OFF_SM;
  float* s1     = ws + OFF_S1;
  float* ctxm   = ws + OFF_CTXM;
  float* gfin   = ws + OFF_GFIN;
  float* ym     = ws + OFF_YM;
  unsigned short* ugbf = (unsigned short*)(ws + OFF_UGBF);
  float2* statp = (float2*)(ws + OFF_STATP);
  float* sct    = ws + OFF_SCT;
  float* upart  = ws + OFF_BIG;
  float* raw    = ws + OFF_BIG;
  float* attn   = ws + OFF_ATTN;
  float* am     = ws + OFF_AM;
  float* part   = ws + OFF_PART;
  float* out_attn = out + (long)NROWS * DIM;

  hipLaunchKernelGGL(k_smean,   dim3(16),        dim3(256), 0, stream, slots, sm, sc7);
  hipLaunchKernelGGL(k_qproj,   dim3(1024),      dim3(256), 0, stream, ipw, ipb, sc7, q7);
  hipLaunchKernelGGL(k_uproj,   dim3(16, 8, 4),  dim3(256), 0, stream, ipw, q7, upart);
  hipLaunchKernelGGL(k_ured,    dim3(16, 9),     dim3(256), 0, stream, upart, lng, u56, ugbf);
  hipLaunchKernelGGL(k_ad,      dim3(56),        dim3(256), 0, stream, u56, q7, lng, lnb, ipb, Aarr, D0arr);
  hipLaunchKernelGGL(k_scores2, dim3(1024),      dim3(256), 0, stream, x, ugbf, raw, statp);
  hipLaunchKernelGGL(k_sepi,    dim3(4096),      dim3(256), 0, stream, raw, statp, Aarr, D0arr, mu, rstd, sct);
  hipLaunchKernelGGL(k_softmax, dim3(448),       dim3(256), 0, stream, sct, attn);
  hipLaunchKernelGGL(k_means,   dim3(64),        dim3(256), 0, stream, attn, am, out_attn);
  hipLaunchKernelGGL(k_s1,      dim3(64),        dim3(256), 0, stream, am, mu, rstd, s1);
  hipLaunchKernelGGL(k_ypart,   dim3(512),       dim3(256), 0, stream, x, am, rstd, part);
  hipLaunchKernelGGL(k_yred,    dim3(256),       dim3(256), 0, stream, part, s1, lng, lnb, ym);
  hipLaunchKernelGGL(k_ctxm,    dim3(1024),      dim3(256), 0, stream, ipw, ipb, ym, ctxm);
  hipLaunchKernelGGL(k_gvec,    dim3(1024),      dim3(256), 0, stream, opw, opb, ctxm, sm, alpha, gfin);
  hipLaunchKernelGGL(k_refine,  dim3(8192),      dim3(256), 0, stream, x, gfin, out);
}